// Round 12
// baseline (148.909 us; speedup 1.0000x reference)
//
#include <hip/hip_runtime.h>
#include <hip/hip_bf16.h>

#define BATCH 1024
#define INPUT_DIM 1024
#define NBK 32
#define KDIM 16

typedef __attribute__((ext_vector_type(8))) short short8;
typedef __attribute__((ext_vector_type(4))) float f32x4;

// u16 quantization of act: u = round(act*QS) + 32768. Bias cancels in |a-c|;
// SAD accumulates integer L1; exp(-L1/QS) = exp2(L1_int * (-log2e/QS)).
#define QS 2048.0f
#define EXPC (-7.0444191e-4f)   // -log2(e)/2048

#if __has_builtin(__builtin_amdgcn_sad_u16)
__device__ __forceinline__ unsigned int sadu16(unsigned int a, unsigned int b,
                                               unsigned int acc) {
    return __builtin_amdgcn_sad_u16(a, b, acc);
}
#else
__device__ __forceinline__ unsigned int sadu16(unsigned int a, unsigned int b,
                                               unsigned int acc) {
    int d0 = (int)(a & 0xFFFFu) - (int)(b & 0xFFFFu);
    int d1 = (int)(a >> 16)     - (int)(b >> 16);
    return acc + (unsigned int)(d0 < 0 ? -d0 : d0) + (unsigned int)(d1 < 0 ? -d1 : d1);
}
#endif

// pack two fp32 -> one u32 holding two bf16 (truncation): 1 v_perm_b32.
__device__ __forceinline__ unsigned int pk_bf16_trunc(float lo, float hi) {
    union { float f; unsigned u; } a, b;
    a.f = lo; b.f = hi;
    return __builtin_amdgcn_perm(b.u, a.u, 0x07060302u);
}

// ---------------------------------------------------------------------------
// INSTRUMENTATION ROUND: R9 bodies verbatim, each wrapped in a runtime
// `niter` loop (idempotent re-execution; same stores each iter). With
// niter=4: T = fill + OH + 4*S  =>  S = (T - T_R9)/3, and any kernel whose
// 4x time > ~42 us becomes visible in rocprof top-5 with its own counters.
// ---------------------------------------------------------------------------

// Kernel 1: act2u[k][b][m] (u16) via bf16 MFMA 16x16x32 (R9-proven).
__global__ __launch_bounds__(256) void gemm_k(const float* __restrict__ x,
                                              const float* __restrict__ W,
                                              unsigned short* __restrict__ act2u,
                                              float* __restrict__ out,
                                              int niter) {
    __shared__ float lds[1536];
    const int bid  = blockIdx.x;
    const int tid  = threadIdx.x;
    const int k    = bid >> 5;
    const int b0   = (bid & 31) * 32;
    const int lane = tid & 63;
    const int w4   = tid >> 6;                 // 0..3: d-quarter
    const int m16  = lane & 15;
    const int quad = lane >> 4;

    for (int it = 0; it < niter; ++it) {
        __syncthreads();   // protect lds WAR across iterations

        // side job: copy x slice into out (each block: 1024 floats, disjoint)
        {
            const int i = bid * 1024 + tid * 4;
            float4 v = *(const float4*)(x + i);
            const int b = i >> 10;
            const int d = i & 1023;
            *(float4*)(out + b * 1056 + d) = v;
        }

        const float* xa0 = x + (b0 + m16) * INPUT_DIM + w4 * 256 + quad * 8;
        const float* xa1 = xa0 + 16 * INPUT_DIM;
        const float* wb  = W + k * (INPUT_DIM * KDIM) + (w4 * 256 + quad * 8) * KDIM + m16;

        f32x4 acc0 = {0.f, 0.f, 0.f, 0.f};
        f32x4 acc1 = {0.f, 0.f, 0.f, 0.f};

#pragma unroll
        for (int s = 0; s < 8; ++s) {
            const float* pa0 = xa0 + s * 32;
            const float* pa1 = xa1 + s * 32;
            const float* pb  = wb + s * 32 * KDIM;
            float4 a0l = *(const float4*)(pa0);
            float4 a0h = *(const float4*)(pa0 + 4);
            float4 a1l = *(const float4*)(pa1);
            float4 a1h = *(const float4*)(pa1 + 4);
            float b0w = pb[0 * KDIM], b1w = pb[1 * KDIM];
            float b2w = pb[2 * KDIM], b3w = pb[3 * KDIM];
            float b4w = pb[4 * KDIM], b5w = pb[5 * KDIM];
            float b6w = pb[6 * KDIM], b7w = pb[7 * KDIM];
            union { unsigned int u[4]; short8 s8; } A0, A1, BV;
            A0.u[0] = pk_bf16_trunc(a0l.x, a0l.y); A0.u[1] = pk_bf16_trunc(a0l.z, a0l.w);
            A0.u[2] = pk_bf16_trunc(a0h.x, a0h.y); A0.u[3] = pk_bf16_trunc(a0h.z, a0h.w);
            A1.u[0] = pk_bf16_trunc(a1l.x, a1l.y); A1.u[1] = pk_bf16_trunc(a1l.z, a1l.w);
            A1.u[2] = pk_bf16_trunc(a1h.x, a1h.y); A1.u[3] = pk_bf16_trunc(a1h.z, a1h.w);
            BV.u[0] = pk_bf16_trunc(b0w, b1w);     BV.u[1] = pk_bf16_trunc(b2w, b3w);
            BV.u[2] = pk_bf16_trunc(b4w, b5w);     BV.u[3] = pk_bf16_trunc(b6w, b7w);
            acc0 = __builtin_amdgcn_mfma_f32_16x16x32_bf16(A0.s8, BV.s8, acc0, 0, 0, 0);
            acc1 = __builtin_amdgcn_mfma_f32_16x16x32_bf16(A1.s8, BV.s8, acc1, 0, 0, 0);
        }

        if (w4 > 0) {
            float* r = &lds[(w4 - 1) * 512 + lane * 8];
            *(float4*)(r)     = make_float4(acc0[0], acc0[1], acc0[2], acc0[3]);
            *(float4*)(r + 4) = make_float4(acc1[0], acc1[1], acc1[2], acc1[3]);
        }
        __syncthreads();
        if (w4 == 0) {
#pragma unroll
            for (int j = 0; j < 3; ++j) {
                const float* r = &lds[j * 512 + lane * 8];
                float4 p0 = *(const float4*)(r);
                float4 p1 = *(const float4*)(r + 4);
                acc0[0] += p0.x; acc0[1] += p0.y; acc0[2] += p0.z; acc0[3] += p0.w;
                acc1[0] += p1.x; acc1[1] += p1.y; acc1[2] += p1.z; acc1[3] += p1.w;
            }
            const int row0 = b0 + quad * 4;
#pragma unroll
            for (int r = 0; r < 4; ++r) {
                float q0 = fminf(fmaxf(acc0[r] * QS, -30000.f), 30000.f);
                float q1 = fminf(fmaxf(acc1[r] * QS, -30000.f), 30000.f);
                act2u[(k * BATCH + row0 + r) * KDIM + m16] =
                    (unsigned short)(32768 + (int)rintf(q0));
                act2u[(k * BATCH + row0 + 16 + r) * KDIM + m16] =
                    (unsigned short)(32768 + (int)rintf(q1));
            }
        }
    }
}

// Kernel 2: pairwise via v_sad_u16, 4 b-rows/thread (R9-proven).
__global__ __launch_bounds__(256) void pairwise_k(const unsigned short* __restrict__ act2u,
                                                  float* __restrict__ part,
                                                  int niter) {
    __shared__ unsigned int cs[32 * 8];  // 1 KB
    const int tid = threadIdx.x;
    const int k   = blockIdx.y;
    const int c0  = blockIdx.x * 32;
    const unsigned short* base = act2u + k * (BATCH * KDIM);

    for (int it = 0; it < niter; ++it) {
        __syncthreads();   // protect cs WAR across iterations

        if (tid < 64) ((uint4*)cs)[tid] = ((const uint4*)(base + c0 * KDIM))[tid];

        unsigned int a[4][8];
#pragma unroll
        for (int r = 0; r < 4; ++r) {
            const uint4* src = (const uint4*)(base + (tid + r * 256) * KDIM);
            uint4 u0 = src[0], u1 = src[1];
            a[r][0] = u0.x; a[r][1] = u0.y; a[r][2] = u0.z; a[r][3] = u0.w;
            a[r][4] = u1.x; a[r][5] = u1.y; a[r][6] = u1.z; a[r][7] = u1.w;
        }
        __syncthreads();

        float f0 = 0.f, f1 = 0.f, f2 = 0.f, f3 = 0.f;
#pragma unroll 2
        for (int c = 0; c < 32; ++c) {
            uint4 q0 = *(const uint4*)&cs[c * 8];
            uint4 q1 = *(const uint4*)&cs[c * 8 + 4];
            unsigned int cr[8] = {q0.x, q0.y, q0.z, q0.w, q1.x, q1.y, q1.z, q1.w};
            unsigned int s0 = 0u, s1 = 0u, s2 = 0u, s3 = 0u;
#pragma unroll
            for (int j = 0; j < 8; ++j) {
                s0 = sadu16(a[0][j], cr[j], s0);
                s1 = sadu16(a[1][j], cr[j], s1);
                s2 = sadu16(a[2][j], cr[j], s2);
                s3 = sadu16(a[3][j], cr[j], s3);
            }
            f0 += exp2f((float)s0 * EXPC);
            f1 += exp2f((float)s1 * EXPC);
            f2 += exp2f((float)s2 * EXPC);
            f3 += exp2f((float)s3 * EXPC);
        }
        float* p = part + blockIdx.x * (NBK * BATCH) + k * BATCH + tid;
        p[0]   = f0;
        p[256] = f1;
        p[512] = f2;
        p[768] = f3;
    }
}

// Kernel 3: out[b][1024+k] = sum over 32 chunks of part[ch][k][b] (proven).
__global__ __launch_bounds__(256) void combine_k(const float* __restrict__ part,
                                                 float* __restrict__ out,
                                                 int niter) {
    const int t = blockIdx.x * 256 + threadIdx.x;   // k*1024 + b, t < 32768
    const int k = t >> 10;
    const int b = t & 1023;
    for (int it = 0; it < niter; ++it) {
        float s = 0.f;
#pragma unroll
        for (int i = 0; i < 32; ++i) s += part[i * (NBK * BATCH) + t];
        out[b * 1056 + 1024 + k] = s;
    }
}

extern "C" void kernel_launch(void* const* d_in, const int* in_sizes, int n_in,
                              void* d_out, int out_size, void* d_ws, size_t ws_size,
                              hipStream_t stream) {
    const float* x = (const float*)d_in[0];
    const float* W = (const float*)d_in[1];
    float* out = (float*)d_out;

    unsigned short* act2u = (unsigned short*)d_ws;                  // 1 MB
    float* part = (float*)((char*)d_ws + 1024 * 1024);              // 4 MB

    const int NITER = 4;   // instrumentation multiplier (idempotent work)
    gemm_k<<<1024, 256, 0, stream>>>(x, W, act2u, out, NITER);
    pairwise_k<<<dim3(32, 32), 256, 0, stream>>>(act2u, part, NITER);
    combine_k<<<128, 256, 0, stream>>>(part, out, NITER);
}

// Round 13
// 94.566 us; speedup vs baseline: 1.5747x; 1.5747x over previous
//
#include <hip/hip_runtime.h>
#include <hip/hip_bf16.h>

#define BATCH 1024
#define INPUT_DIM 1024
#define NBK 32
#define KDIM 16

typedef __attribute__((ext_vector_type(8))) short short8;
typedef __attribute__((ext_vector_type(4))) float f32x4;

// u16 quantization of act: u = round(act*QS) + 32768. Bias cancels in |a-c|;
// SAD accumulates integer L1; exp(-L1/QS) = exp2(L1_int * (-log2e/QS)).
#define QS 2048.0f
#define EXPC (-7.0444191e-4f)   // -log2(e)/2048

#if __has_builtin(__builtin_amdgcn_sad_u16)
__device__ __forceinline__ unsigned int sadu16(unsigned int a, unsigned int b,
                                               unsigned int acc) {
    return __builtin_amdgcn_sad_u16(a, b, acc);
}
#else
__device__ __forceinline__ unsigned int sadu16(unsigned int a, unsigned int b,
                                               unsigned int acc) {
    int d0 = (int)(a & 0xFFFFu) - (int)(b & 0xFFFFu);
    int d1 = (int)(a >> 16)     - (int)(b >> 16);
    return acc + (unsigned int)(d0 < 0 ? -d0 : d0) + (unsigned int)(d1 < 0 ? -d1 : d1);
}
#endif

// Raw v_exp_f32 (exp2). Arguments here are in [-43, 0]: normal range, no
// OCML denorm/clamp sequence needed. Saves ~4 VALU ops per call vs exp2f.
#if __has_builtin(__builtin_amdgcn_exp2f)
__device__ __forceinline__ float fast_exp2(float x) {
    return __builtin_amdgcn_exp2f(x);
}
#else
__device__ __forceinline__ float fast_exp2(float x) { return exp2f(x); }
#endif

// pack two fp32 -> one u32 holding two bf16 (truncation): 1 v_perm_b32.
__device__ __forceinline__ unsigned int pk_bf16_trunc(float lo, float hi) {
    union { float f; unsigned u; } a, b;
    a.f = lo; b.f = hi;
    return __builtin_amdgcn_perm(b.u, a.u, 0x07060302u);
}

// ---------------------------------------------------------------------------
// Kernel 1: act2u[k][b][m] (u16) via bf16 MFMA 16x16x32 — R9 VERBATIM (96.5
// proven; R10's LDS-staging variant regressed). Direct fp32 reads + v_perm
// trunc-packs; 4 waves split d 4-way, LDS cross-wave reduce + u16 quantize.
// Side job: each block copies a 4 KB slice of x -> out[b][0:1024].
// Measured (R12 niter algebra): marginal compute ~0.4 us — ramp-dominated.
// ---------------------------------------------------------------------------
__global__ __launch_bounds__(256) void gemm_k(const float* __restrict__ x,
                                              const float* __restrict__ W,
                                              unsigned short* __restrict__ act2u,
                                              float* __restrict__ out) {
    __shared__ float lds[1536];
    const int bid  = blockIdx.x;
    const int tid  = threadIdx.x;
    const int k    = bid >> 5;
    const int b0   = (bid & 31) * 32;
    const int lane = tid & 63;
    const int w4   = tid >> 6;                 // 0..3: d-quarter
    const int m16  = lane & 15;
    const int quad = lane >> 4;

    // side job: copy x slice into out (each block: 1024 floats, disjoint)
    {
        const int i = bid * 1024 + tid * 4;
        float4 v = *(const float4*)(x + i);
        const int b = i >> 10;
        const int d = i & 1023;
        *(float4*)(out + b * 1056 + d) = v;
    }

    const float* xa0 = x + (b0 + m16) * INPUT_DIM + w4 * 256 + quad * 8;
    const float* xa1 = xa0 + 16 * INPUT_DIM;
    const float* wb  = W + k * (INPUT_DIM * KDIM) + (w4 * 256 + quad * 8) * KDIM + m16;

    f32x4 acc0 = {0.f, 0.f, 0.f, 0.f};
    f32x4 acc1 = {0.f, 0.f, 0.f, 0.f};

#pragma unroll
    for (int s = 0; s < 8; ++s) {
        const float* pa0 = xa0 + s * 32;
        const float* pa1 = xa1 + s * 32;
        const float* pb  = wb + s * 32 * KDIM;
        float4 a0l = *(const float4*)(pa0);
        float4 a0h = *(const float4*)(pa0 + 4);
        float4 a1l = *(const float4*)(pa1);
        float4 a1h = *(const float4*)(pa1 + 4);
        float b0w = pb[0 * KDIM], b1w = pb[1 * KDIM];
        float b2w = pb[2 * KDIM], b3w = pb[3 * KDIM];
        float b4w = pb[4 * KDIM], b5w = pb[5 * KDIM];
        float b6w = pb[6 * KDIM], b7w = pb[7 * KDIM];
        union { unsigned int u[4]; short8 s8; } A0, A1, BV;
        A0.u[0] = pk_bf16_trunc(a0l.x, a0l.y); A0.u[1] = pk_bf16_trunc(a0l.z, a0l.w);
        A0.u[2] = pk_bf16_trunc(a0h.x, a0h.y); A0.u[3] = pk_bf16_trunc(a0h.z, a0h.w);
        A1.u[0] = pk_bf16_trunc(a1l.x, a1l.y); A1.u[1] = pk_bf16_trunc(a1l.z, a1l.w);
        A1.u[2] = pk_bf16_trunc(a1h.x, a1h.y); A1.u[3] = pk_bf16_trunc(a1h.z, a1h.w);
        BV.u[0] = pk_bf16_trunc(b0w, b1w);     BV.u[1] = pk_bf16_trunc(b2w, b3w);
        BV.u[2] = pk_bf16_trunc(b4w, b5w);     BV.u[3] = pk_bf16_trunc(b6w, b7w);
        acc0 = __builtin_amdgcn_mfma_f32_16x16x32_bf16(A0.s8, BV.s8, acc0, 0, 0, 0);
        acc1 = __builtin_amdgcn_mfma_f32_16x16x32_bf16(A1.s8, BV.s8, acc1, 0, 0, 0);
    }

    if (w4 > 0) {
        float* r = &lds[(w4 - 1) * 512 + lane * 8];
        *(float4*)(r)     = make_float4(acc0[0], acc0[1], acc0[2], acc0[3]);
        *(float4*)(r + 4) = make_float4(acc1[0], acc1[1], acc1[2], acc1[3]);
    }
    __syncthreads();
    if (w4 == 0) {
#pragma unroll
        for (int j = 0; j < 3; ++j) {
            const float* r = &lds[j * 512 + lane * 8];
            float4 p0 = *(const float4*)(r);
            float4 p1 = *(const float4*)(r + 4);
            acc0[0] += p0.x; acc0[1] += p0.y; acc0[2] += p0.z; acc0[3] += p0.w;
            acc1[0] += p1.x; acc1[1] += p1.y; acc1[2] += p1.z; acc1[3] += p1.w;
        }
        const int row0 = b0 + quad * 4;
#pragma unroll
        for (int r = 0; r < 4; ++r) {
            float q0 = fminf(fmaxf(acc0[r] * QS, -30000.f), 30000.f);
            float q1 = fminf(fmaxf(acc1[r] * QS, -30000.f), 30000.f);
            act2u[(k * BATCH + row0 + r) * KDIM + m16] =
                (unsigned short)(32768 + (int)rintf(q0));
            act2u[(k * BATCH + row0 + 16 + r) * KDIM + m16] =
                (unsigned short)(32768 + (int)rintf(q1));
        }
    }
}

// ---------------------------------------------------------------------------
// Kernel 2: pairwise via v_sad_u16 — R12 measured: VALU-issue-bound
// (VALUBusy 78%) at ~2.3x ideal instruction count. This round: lean codegen.
//  * fast_exp2 = raw v_exp_f32 (args in [-43,0], normal range) — removes the
//    OCML exp2f range-check sequence (~4 VALU x4 accs per c-iter).
//  * unroll 4 — deeper ds_read lookahead to close the 22% issue-idle.
//  * all 256 threads stage (1 uint4 each 1/4 rate) — trims prologue.
// grid (chunk=32, k=32) = 1024 blocks x 256 thr; 4 b-rows/thread; coalesced
// part stores (no atomics).
// ---------------------------------------------------------------------------
__global__ __launch_bounds__(256) void pairwise_k(const unsigned short* __restrict__ act2u,
                                                  float* __restrict__ part) {
    __shared__ unsigned int cs[32 * 8];  // 1 KB
    const int tid = threadIdx.x;
    const int k   = blockIdx.y;
    const int c0  = blockIdx.x * 32;
    const unsigned short* base = act2u + k * (BATCH * KDIM);

    if (tid < 64) ((uint4*)cs)[tid] = ((const uint4*)(base + c0 * KDIM))[tid];

    unsigned int a[4][8];
#pragma unroll
    for (int r = 0; r < 4; ++r) {
        const uint4* src = (const uint4*)(base + (tid + r * 256) * KDIM);
        uint4 u0 = src[0], u1 = src[1];
        a[r][0] = u0.x; a[r][1] = u0.y; a[r][2] = u0.z; a[r][3] = u0.w;
        a[r][4] = u1.x; a[r][5] = u1.y; a[r][6] = u1.z; a[r][7] = u1.w;
    }
    __syncthreads();

    float f0 = 0.f, f1 = 0.f, f2 = 0.f, f3 = 0.f;
#pragma unroll 4
    for (int c = 0; c < 32; ++c) {
        uint4 q0 = *(const uint4*)&cs[c * 8];
        uint4 q1 = *(const uint4*)&cs[c * 8 + 4];
        unsigned int cr[8] = {q0.x, q0.y, q0.z, q0.w, q1.x, q1.y, q1.z, q1.w};
        unsigned int s0 = 0u, s1 = 0u, s2 = 0u, s3 = 0u;
#pragma unroll
        for (int j = 0; j < 8; ++j) {
            s0 = sadu16(a[0][j], cr[j], s0);
            s1 = sadu16(a[1][j], cr[j], s1);
            s2 = sadu16(a[2][j], cr[j], s2);
            s3 = sadu16(a[3][j], cr[j], s3);
        }
        f0 += fast_exp2((float)s0 * EXPC);
        f1 += fast_exp2((float)s1 * EXPC);
        f2 += fast_exp2((float)s2 * EXPC);
        f3 += fast_exp2((float)s3 * EXPC);
    }
    float* p = part + blockIdx.x * (NBK * BATCH) + k * BATCH + tid;
    p[0]   = f0;
    p[256] = f1;
    p[512] = f2;
    p[768] = f3;
}

// ---------------------------------------------------------------------------
// Kernel 3: out[b][1024+k] = sum over 32 chunks of part[ch][k][b] (proven;
// R12 algebra: marginal compute ~0.1 us, ramp-dominated).
// ---------------------------------------------------------------------------
__global__ __launch_bounds__(256) void combine_k(const float* __restrict__ part,
                                                 float* __restrict__ out) {
    const int t = blockIdx.x * 256 + threadIdx.x;   // k*1024 + b, t < 32768
    const int k = t >> 10;
    const int b = t & 1023;
    float s = 0.f;
#pragma unroll
    for (int i = 0; i < 32; ++i) s += part[i * (NBK * BATCH) + t];
    out[b * 1056 + 1024 + k] = s;
}

extern "C" void kernel_launch(void* const* d_in, const int* in_sizes, int n_in,
                              void* d_out, int out_size, void* d_ws, size_t ws_size,
                              hipStream_t stream) {
    const float* x = (const float*)d_in[0];
    const float* W = (const float*)d_in[1];
    float* out = (float*)d_out;

    unsigned short* act2u = (unsigned short*)d_ws;                  // 1 MB
    float* part = (float*)((char*)d_ws + 1024 * 1024);              // 4 MB

    gemm_k<<<1024, 256, 0, stream>>>(x, W, act2u, out);
    pairwise_k<<<dim3(32, 32), 256, 0, stream>>>(act2u, part);
    combine_k<<<128, 256, 0, stream>>>(part, out);
}

// Round 14
// 88.007 us; speedup vs baseline: 1.6920x; 1.0745x over previous
//
#include <hip/hip_runtime.h>
#include <hip/hip_bf16.h>

#define BATCH 1024
#define INPUT_DIM 1024
#define NBK 32
#define KDIM 16

typedef __attribute__((ext_vector_type(8))) short short8;
typedef __attribute__((ext_vector_type(4))) float f32x4;

// u8 quantization of act: u = round(act*QS8) + 128, clamped. Bias cancels in
// |a-c|; v_sad_u8 accumulates integer L1 4 bytes/instr;
// exp(-L1/QS8) = exp2(L1_int * (-log2e/QS8)).
#define QS8 16.0f
#define EXPC8 (-0.090168443f)   // -log2(e)/16

#if __has_builtin(__builtin_amdgcn_sad_u8)
__device__ __forceinline__ unsigned int sadu8(unsigned int a, unsigned int b,
                                              unsigned int acc) {
    return __builtin_amdgcn_sad_u8(a, b, acc);
}
#else
__device__ __forceinline__ unsigned int sadu8(unsigned int a, unsigned int b,
                                              unsigned int acc) {
#pragma unroll
    for (int i = 0; i < 4; ++i) {
        int av = (a >> (8 * i)) & 0xFF, bv = (b >> (8 * i)) & 0xFF;
        int d = av - bv;
        acc += (unsigned int)(d < 0 ? -d : d);
    }
    return acc;
}
#endif

// Raw v_exp_f32 (exp2). Args in [-368, 0] here; for s_int large exp2
// underflows to 0 cleanly (no denorm fixup needed for our sums).
#if __has_builtin(__builtin_amdgcn_exp2f)
__device__ __forceinline__ float fast_exp2(float x) {
    return __builtin_amdgcn_exp2f(x);
}
#else
__device__ __forceinline__ float fast_exp2(float x) { return exp2f(x); }
#endif

// pack two fp32 -> one u32 holding two bf16 (truncation): 1 v_perm_b32.
__device__ __forceinline__ unsigned int pk_bf16_trunc(float lo, float hi) {
    union { float f; unsigned u; } a, b;
    a.f = lo; b.f = hi;
    return __builtin_amdgcn_perm(b.u, a.u, 0x07060302u);
}

// ---------------------------------------------------------------------------
// Kernel 1: act2b[k][b][m] (u8) via bf16 MFMA 16x16x32 — R9/R13 structure
// (proven), epilogue now quantizes to u8 (QS8=16; diagonal pairs stay exact
// since both rows quantize identically). Direct fp32 reads + v_perm packs;
// 4 waves split d 4-way, LDS cross-wave reduce.
// Side job: each block copies a 4 KB slice of x -> out[b][0:1024].
// ---------------------------------------------------------------------------
__global__ __launch_bounds__(256) void gemm_k(const float* __restrict__ x,
                                              const float* __restrict__ W,
                                              unsigned char* __restrict__ act2b,
                                              float* __restrict__ out) {
    __shared__ float lds[1536];
    const int bid  = blockIdx.x;
    const int tid  = threadIdx.x;
    const int k    = bid >> 5;
    const int b0   = (bid & 31) * 32;
    const int lane = tid & 63;
    const int w4   = tid >> 6;                 // 0..3: d-quarter
    const int m16  = lane & 15;
    const int quad = lane >> 4;

    // side job: copy x slice into out (each block: 1024 floats, disjoint)
    {
        const int i = bid * 1024 + tid * 4;
        float4 v = *(const float4*)(x + i);
        const int b = i >> 10;
        const int d = i & 1023;
        *(float4*)(out + b * 1056 + d) = v;
    }

    const float* xa0 = x + (b0 + m16) * INPUT_DIM + w4 * 256 + quad * 8;
    const float* xa1 = xa0 + 16 * INPUT_DIM;
    const float* wb  = W + k * (INPUT_DIM * KDIM) + (w4 * 256 + quad * 8) * KDIM + m16;

    f32x4 acc0 = {0.f, 0.f, 0.f, 0.f};
    f32x4 acc1 = {0.f, 0.f, 0.f, 0.f};

#pragma unroll
    for (int s = 0; s < 8; ++s) {
        const float* pa0 = xa0 + s * 32;
        const float* pa1 = xa1 + s * 32;
        const float* pb  = wb + s * 32 * KDIM;
        float4 a0l = *(const float4*)(pa0);
        float4 a0h = *(const float4*)(pa0 + 4);
        float4 a1l = *(const float4*)(pa1);
        float4 a1h = *(const float4*)(pa1 + 4);
        float b0w = pb[0 * KDIM], b1w = pb[1 * KDIM];
        float b2w = pb[2 * KDIM], b3w = pb[3 * KDIM];
        float b4w = pb[4 * KDIM], b5w = pb[5 * KDIM];
        float b6w = pb[6 * KDIM], b7w = pb[7 * KDIM];
        union { unsigned int u[4]; short8 s8; } A0, A1, BV;
        A0.u[0] = pk_bf16_trunc(a0l.x, a0l.y); A0.u[1] = pk_bf16_trunc(a0l.z, a0l.w);
        A0.u[2] = pk_bf16_trunc(a0h.x, a0h.y); A0.u[3] = pk_bf16_trunc(a0h.z, a0h.w);
        A1.u[0] = pk_bf16_trunc(a1l.x, a1l.y); A1.u[1] = pk_bf16_trunc(a1l.z, a1l.w);
        A1.u[2] = pk_bf16_trunc(a1h.x, a1h.y); A1.u[3] = pk_bf16_trunc(a1h.z, a1h.w);
        BV.u[0] = pk_bf16_trunc(b0w, b1w);     BV.u[1] = pk_bf16_trunc(b2w, b3w);
        BV.u[2] = pk_bf16_trunc(b4w, b5w);     BV.u[3] = pk_bf16_trunc(b6w, b7w);
        acc0 = __builtin_amdgcn_mfma_f32_16x16x32_bf16(A0.s8, BV.s8, acc0, 0, 0, 0);
        acc1 = __builtin_amdgcn_mfma_f32_16x16x32_bf16(A1.s8, BV.s8, acc1, 0, 0, 0);
    }

    if (w4 > 0) {
        float* r = &lds[(w4 - 1) * 512 + lane * 8];
        *(float4*)(r)     = make_float4(acc0[0], acc0[1], acc0[2], acc0[3]);
        *(float4*)(r + 4) = make_float4(acc1[0], acc1[1], acc1[2], acc1[3]);
    }
    __syncthreads();
    if (w4 == 0) {
#pragma unroll
        for (int j = 0; j < 3; ++j) {
            const float* r = &lds[j * 512 + lane * 8];
            float4 p0 = *(const float4*)(r);
            float4 p1 = *(const float4*)(r + 4);
            acc0[0] += p0.x; acc0[1] += p0.y; acc0[2] += p0.z; acc0[3] += p0.w;
            acc1[0] += p1.x; acc1[1] += p1.y; acc1[2] += p1.z; acc1[3] += p1.w;
        }
        const int row0 = b0 + quad * 4;
#pragma unroll
        for (int r = 0; r < 4; ++r) {
            float q0 = fminf(fmaxf(acc0[r] * QS8, -127.f), 127.f);
            float q1 = fminf(fmaxf(acc1[r] * QS8, -127.f), 127.f);
            act2b[(k * BATCH + row0 + r) * KDIM + m16] =
                (unsigned char)(128 + (int)rintf(q0));
            act2b[(k * BATCH + row0 + 16 + r) * KDIM + m16] =
                (unsigned char)(128 + (int)rintf(q1));
        }
    }
}

// ---------------------------------------------------------------------------
// Kernel 2: pairwise via v_sad_u8 — 4 bytes/instr: 16-elem L1 in 4 SADs
// (vs 8 with u16). Per-pair ops 12 -> 8; LDS c-row traffic halved (1
// ds_read_b128 per c). 4 b-rows/thread, fast_exp2 epilogue, coalesced part
// stores. grid (chunk=32, k=32) = 1024 blocks x 256 thr.
// ---------------------------------------------------------------------------
__global__ __launch_bounds__(256) void pairwise_k(const unsigned char* __restrict__ act2b,
                                                  float* __restrict__ part) {
    __shared__ unsigned int cs[32 * 4];  // 512 B: 32 rows x 16 u8
    const int tid = threadIdx.x;
    const int k   = blockIdx.y;
    const int c0  = blockIdx.x * 32;
    const unsigned char* base = act2b + k * (BATCH * KDIM);

    if (tid < 32) ((uint4*)cs)[tid] = ((const uint4*)(base + c0 * KDIM))[tid];

    unsigned int a[4][4];
#pragma unroll
    for (int r = 0; r < 4; ++r) {
        uint4 u = *(const uint4*)(base + (tid + r * 256) * KDIM);
        a[r][0] = u.x; a[r][1] = u.y; a[r][2] = u.z; a[r][3] = u.w;
    }
    __syncthreads();

    float f0 = 0.f, f1 = 0.f, f2 = 0.f, f3 = 0.f;
#pragma unroll 4
    for (int c = 0; c < 32; ++c) {
        uint4 q = *(const uint4*)&cs[c * 4];
        unsigned int cr[4] = {q.x, q.y, q.z, q.w};
        unsigned int s0 = 0u, s1 = 0u, s2 = 0u, s3 = 0u;
#pragma unroll
        for (int j = 0; j < 4; ++j) {
            s0 = sadu8(a[0][j], cr[j], s0);
            s1 = sadu8(a[1][j], cr[j], s1);
            s2 = sadu8(a[2][j], cr[j], s2);
            s3 = sadu8(a[3][j], cr[j], s3);
        }
        f0 += fast_exp2((float)s0 * EXPC8);
        f1 += fast_exp2((float)s1 * EXPC8);
        f2 += fast_exp2((float)s2 * EXPC8);
        f3 += fast_exp2((float)s3 * EXPC8);
    }
    float* p = part + blockIdx.x * (NBK * BATCH) + k * BATCH + tid;
    p[0]   = f0;
    p[256] = f1;
    p[512] = f2;
    p[768] = f3;
}

// ---------------------------------------------------------------------------
// Kernel 3: out[b][1024+k] = sum over 32 chunks of part[ch][k][b] (proven).
// ---------------------------------------------------------------------------
__global__ __launch_bounds__(256) void combine_k(const float* __restrict__ part,
                                                 float* __restrict__ out) {
    const int t = blockIdx.x * 256 + threadIdx.x;   // k*1024 + b, t < 32768
    const int k = t >> 10;
    const int b = t & 1023;
    float s = 0.f;
#pragma unroll
    for (int i = 0; i < 32; ++i) s += part[i * (NBK * BATCH) + t];
    out[b * 1056 + 1024 + k] = s;
}

extern "C" void kernel_launch(void* const* d_in, const int* in_sizes, int n_in,
                              void* d_out, int out_size, void* d_ws, size_t ws_size,
                              hipStream_t stream) {
    const float* x = (const float*)d_in[0];
    const float* W = (const float*)d_in[1];
    float* out = (float*)d_out;

    unsigned char* act2b = (unsigned char*)d_ws;                    // 512 KB
    float* part = (float*)((char*)d_ws + 512 * 1024);               // 4 MB

    gemm_k<<<1024, 256, 0, stream>>>(x, W, act2b, out);
    pairwise_k<<<dim3(32, 32), 256, 0, stream>>>(act2b, part);
    combine_k<<<128, 256, 0, stream>>>(part, out);
}

// Round 15
// 85.064 us; speedup vs baseline: 1.7505x; 1.0346x over previous
//
#include <hip/hip_runtime.h>
#include <hip/hip_bf16.h>

#define BATCH 1024
#define INPUT_DIM 1024
#define NBK 32
#define KDIM 16

typedef __attribute__((ext_vector_type(8))) short short8;
typedef __attribute__((ext_vector_type(4))) float f32x4;

// u8 quantization of act: u = round(act*QS8) + 128, clamped. Bias cancels in
// |a-c|; v_sad_u8 accumulates integer L1 4 bytes/instr;
// exp(-L1/QS8) = exp2(L1_int * (-log2e/QS8)).
#define QS8 16.0f
#define EXPC8 (-0.090168443f)   // -log2(e)/16

#if __has_builtin(__builtin_amdgcn_sad_u8)
__device__ __forceinline__ unsigned int sadu8(unsigned int a, unsigned int b,
                                              unsigned int acc) {
    return __builtin_amdgcn_sad_u8(a, b, acc);
}
#else
__device__ __forceinline__ unsigned int sadu8(unsigned int a, unsigned int b,
                                              unsigned int acc) {
#pragma unroll
    for (int i = 0; i < 4; ++i) {
        int av = (a >> (8 * i)) & 0xFF, bv = (b >> (8 * i)) & 0xFF;
        int d = av - bv;
        acc += (unsigned int)(d < 0 ? -d : d);
    }
    return acc;
}
#endif

#if __has_builtin(__builtin_amdgcn_exp2f)
__device__ __forceinline__ float fast_exp2(float x) {
    return __builtin_amdgcn_exp2f(x);
}
#else
__device__ __forceinline__ float fast_exp2(float x) { return exp2f(x); }
#endif

// pack two fp32 -> one u32 holding two bf16 (truncation): 1 v_perm_b32.
__device__ __forceinline__ unsigned int pk_bf16_trunc(float lo, float hi) {
    union { float f; unsigned u; } a, b;
    a.f = lo; b.f = hi;
    return __builtin_amdgcn_perm(b.u, a.u, 0x07060302u);
}

// ---------------------------------------------------------------------------
// Kernel 1: act2b[k][b][m] (u8, QS8=16) via bf16 MFMA 16x16x32 — R14 VERBATIM
// (88.0-proven). Direct fp32 reads + v_perm packs; 4 waves split d 4-way,
// LDS cross-wave reduce; u8 quantize epilogue.
// Side job: each block copies a 4 KB slice of x -> out[b][0:1024].
// ---------------------------------------------------------------------------
__global__ __launch_bounds__(256) void gemm_k(const float* __restrict__ x,
                                              const float* __restrict__ W,
                                              unsigned char* __restrict__ act2b,
                                              float* __restrict__ out) {
    __shared__ float lds[1536];
    const int bid  = blockIdx.x;
    const int tid  = threadIdx.x;
    const int k    = bid >> 5;
    const int b0   = (bid & 31) * 32;
    const int lane = tid & 63;
    const int w4   = tid >> 6;                 // 0..3: d-quarter
    const int m16  = lane & 15;
    const int quad = lane >> 4;

    // side job: copy x slice into out (each block: 1024 floats, disjoint)
    {
        const int i = bid * 1024 + tid * 4;
        float4 v = *(const float4*)(x + i);
        const int b = i >> 10;
        const int d = i & 1023;
        *(float4*)(out + b * 1056 + d) = v;
    }

    const float* xa0 = x + (b0 + m16) * INPUT_DIM + w4 * 256 + quad * 8;
    const float* xa1 = xa0 + 16 * INPUT_DIM;
    const float* wb  = W + k * (INPUT_DIM * KDIM) + (w4 * 256 + quad * 8) * KDIM + m16;

    f32x4 acc0 = {0.f, 0.f, 0.f, 0.f};
    f32x4 acc1 = {0.f, 0.f, 0.f, 0.f};

#pragma unroll
    for (int s = 0; s < 8; ++s) {
        const float* pa0 = xa0 + s * 32;
        const float* pa1 = xa1 + s * 32;
        const float* pb  = wb + s * 32 * KDIM;
        float4 a0l = *(const float4*)(pa0);
        float4 a0h = *(const float4*)(pa0 + 4);
        float4 a1l = *(const float4*)(pa1);
        float4 a1h = *(const float4*)(pa1 + 4);
        float b0w = pb[0 * KDIM], b1w = pb[1 * KDIM];
        float b2w = pb[2 * KDIM], b3w = pb[3 * KDIM];
        float b4w = pb[4 * KDIM], b5w = pb[5 * KDIM];
        float b6w = pb[6 * KDIM], b7w = pb[7 * KDIM];
        union { unsigned int u[4]; short8 s8; } A0, A1, BV;
        A0.u[0] = pk_bf16_trunc(a0l.x, a0l.y); A0.u[1] = pk_bf16_trunc(a0l.z, a0l.w);
        A0.u[2] = pk_bf16_trunc(a0h.x, a0h.y); A0.u[3] = pk_bf16_trunc(a0h.z, a0h.w);
        A1.u[0] = pk_bf16_trunc(a1l.x, a1l.y); A1.u[1] = pk_bf16_trunc(a1l.z, a1l.w);
        A1.u[2] = pk_bf16_trunc(a1h.x, a1h.y); A1.u[3] = pk_bf16_trunc(a1h.z, a1h.w);
        BV.u[0] = pk_bf16_trunc(b0w, b1w);     BV.u[1] = pk_bf16_trunc(b2w, b3w);
        BV.u[2] = pk_bf16_trunc(b4w, b5w);     BV.u[3] = pk_bf16_trunc(b6w, b7w);
        acc0 = __builtin_amdgcn_mfma_f32_16x16x32_bf16(A0.s8, BV.s8, acc0, 0, 0, 0);
        acc1 = __builtin_amdgcn_mfma_f32_16x16x32_bf16(A1.s8, BV.s8, acc1, 0, 0, 0);
    }

    if (w4 > 0) {
        float* r = &lds[(w4 - 1) * 512 + lane * 8];
        *(float4*)(r)     = make_float4(acc0[0], acc0[1], acc0[2], acc0[3]);
        *(float4*)(r + 4) = make_float4(acc1[0], acc1[1], acc1[2], acc1[3]);
    }
    __syncthreads();
    if (w4 == 0) {
#pragma unroll
        for (int j = 0; j < 3; ++j) {
            const float* r = &lds[j * 512 + lane * 8];
            float4 p0 = *(const float4*)(r);
            float4 p1 = *(const float4*)(r + 4);
            acc0[0] += p0.x; acc0[1] += p0.y; acc0[2] += p0.z; acc0[3] += p0.w;
            acc1[0] += p1.x; acc1[1] += p1.y; acc1[2] += p1.z; acc1[3] += p1.w;
        }
        const int row0 = b0 + quad * 4;
#pragma unroll
        for (int r = 0; r < 4; ++r) {
            float q0 = fminf(fmaxf(acc0[r] * QS8, -127.f), 127.f);
            float q1 = fminf(fmaxf(acc1[r] * QS8, -127.f), 127.f);
            act2b[(k * BATCH + row0 + r) * KDIM + m16] =
                (unsigned char)(128 + (int)rintf(q0));
            act2b[(k * BATCH + row0 + 16 + r) * KDIM + m16] =
                (unsigned char)(128 + (int)rintf(q1));
        }
    }
}

// ---------------------------------------------------------------------------
// Kernel 2: pairfull — complete features in one block (no part buffer, no
// combine dispatch; plain scattered stores, NOT atomics — R7's lesson).
// grid (bt=16, k=32) = 512 blocks x 512 thr (8 waves; 2 blocks/CU,
// 4 waves/SIMD — same occupancy as R14 pairwise). Block stages the whole
// k-slice (1024 c-rows u8 = 16 KB) once; thread = (row = tid&63,
// cq = tid>>6) accumulates its row over c in [cq*128, cq*128+128).
// A wave is one cq group -> all 64 lanes read the SAME cs address
// (broadcast, conflict-free). 8 partials per row reduced via 2 KB LDS,
// then direct store to out[b*1056+1024+k] (32k 4-B stores total).
// Per-pair cost unchanged from R14 (~8.5 VALU); a-row regs 16 -> 4.
// ---------------------------------------------------------------------------
__global__ __launch_bounds__(512) void pairfull_k(const unsigned char* __restrict__ act2b,
                                                  float* __restrict__ out) {
    __shared__ unsigned int cs[1024 * 4];   // 16 KB: full k-slice, u8 rows
    __shared__ float red[8 * 64];           // 2 KB: per-row partials
    const int tid = threadIdx.x;
    const int k   = blockIdx.y;
    const int bt  = blockIdx.x;
    const int row = tid & 63;
    const int cq  = tid >> 6;               // 0..7: c-eighth (== wave id)
    const unsigned char* base = act2b + k * (BATCH * KDIM);

    // stage all 1024 c-rows (16 KB), coalesced: 512 thr x 2 uint4
    ((uint4*)cs)[tid]       = ((const uint4*)base)[tid];
    ((uint4*)cs)[tid + 512] = ((const uint4*)base)[tid + 512];

    // own row (4 u32 = 16 u8)
    uint4 u = *(const uint4*)(base + (bt * 64 + row) * KDIM);
    const unsigned int a0 = u.x, a1 = u.y, a2 = u.z, a3 = u.w;
    __syncthreads();

    float f = 0.f;
    const unsigned int* cbase = cs + cq * 128 * 4;
#pragma unroll 4
    for (int c = 0; c < 128; ++c) {
        uint4 q = *(const uint4*)&cbase[c * 4];
        unsigned int s = 0u;
        s = sadu8(a0, q.x, s);
        s = sadu8(a1, q.y, s);
        s = sadu8(a2, q.z, s);
        s = sadu8(a3, q.w, s);
        f += fast_exp2((float)s * EXPC8);
    }

    red[cq * 64 + row] = f;
    __syncthreads();
    if (tid < 64) {
        float s = 0.f;
#pragma unroll
        for (int j = 0; j < 8; ++j) s += red[j * 64 + tid];
        out[(bt * 64 + tid) * 1056 + 1024 + k] = s;
    }
}

extern "C" void kernel_launch(void* const* d_in, const int* in_sizes, int n_in,
                              void* d_out, int out_size, void* d_ws, size_t ws_size,
                              hipStream_t stream) {
    const float* x = (const float*)d_in[0];
    const float* W = (const float*)d_in[1];
    float* out = (float*)d_out;

    unsigned char* act2b = (unsigned char*)d_ws;    // 512 KB

    gemm_k<<<1024, 256, 0, stream>>>(x, W, act2b, out);
    pairfull_k<<<dim3(16, 32), 512, 0, stream>>>(act2b, out);
}